// Round 1
// baseline (287.794 us; speedup 1.0000x reference)
//
#include <hip/hip_runtime.h>
#include <hip/hip_bf16.h>

typedef float f32x4 __attribute__((ext_vector_type(4)));
typedef short s16x8 __attribute__((ext_vector_type(8)));

#define NROWS 8192
#define MCOLS 8192
#define DIM   128
#define NEGV  1e9f

#define BI 32
#define BJ 128
#define LSTRIDE 136                 // 128 + 8 bf16 pad -> 272B row stride (17 quads, conflict-free)
#define SMEM_VT_OFF (128*LSTRIDE*2) // 34816
#define SMEM_P_OFF  (2*128*LSTRIDE*2) // 69632
#define SMEM_TOTAL  (SMEM_P_OFF + 8*16*40*2) // 79872

// ---- prep: per-row norm + scale + bf16 convert (row-major out) ----
__global__ void prep_scale_rows(const float* __restrict__ x,
                                const float* __restrict__ beta,
                                __hip_bfloat16* __restrict__ outbf) {
    int row = blockIdx.x * 4 + (threadIdx.x >> 6);
    int l = threadIdx.x & 63;
    const float* xr = x + (size_t)row * DIM;
    float x0 = xr[l], x1 = xr[l + 64];
    float ss = x0 * x0 + x1 * x1;
#pragma unroll
    for (int off = 32; off >= 1; off >>= 1) ss += __shfl_xor(ss, off);
    float s = (beta ? beta[0] : 1.0f) / sqrtf(ss);
    __hip_bfloat16* o = outbf + (size_t)row * DIM;
    o[l]      = __float2bfloat16(x0 * s);
    o[l + 64] = __float2bfloat16(x1 * s);
}

// ---- prep: transpose xj -> Vt[d][j] bf16 (raw values) ----
__global__ void prep_vt(const float* __restrict__ xj, __hip_bfloat16* __restrict__ vt) {
    __shared__ float tile[64][65];
    int j0 = blockIdx.x * 64;
    int d0 = blockIdx.y * 64;
    int t = threadIdx.x; // 256
#pragma unroll
    for (int c = 0; c < 16; ++c) {
        int idx = t + 256 * c;
        int jr = idx >> 6, dc = idx & 63;
        tile[jr][dc] = xj[(size_t)(j0 + jr) * DIM + d0 + dc];
    }
    __syncthreads();
#pragma unroll
    for (int c = 0; c < 16; ++c) {
        int idx = t + 256 * c;
        int dr = idx >> 6, jc = idx & 63;
        vt[(size_t)(d0 + dr) * MCOLS + j0 + jc] = __float2bfloat16(tile[jc][dr]);
    }
}

// ---- flash attention with adjacency mask ----
__launch_bounds__(512)
__global__ void flash_attn(const __hip_bfloat16* __restrict__ Qbf,
                           const __hip_bfloat16* __restrict__ Kbf,
                           const __hip_bfloat16* __restrict__ Vt,
                           const int* __restrict__ adj,
                           float* __restrict__ out) {
    __shared__ char smem[SMEM_TOTAL];
    unsigned short* Klds = (unsigned short*)smem;
    unsigned short* Vlds = (unsigned short*)(smem + SMEM_VT_OFF);
    __hip_bfloat16* Plds = (__hip_bfloat16*)(smem + SMEM_P_OFF);

    const int tid = threadIdx.x;
    const int w    = tid >> 6;
    const int lane = tid & 63;
    const int g    = lane >> 4;
    const int ln   = lane & 15;
    const int wi   = w >> 2;  // 0..1 row group
    const int wj   = w & 3;   // 0..3 j slice
    const int i0   = blockIdx.x * BI;
    const int ri0  = i0 + wi * 16;

    // Q fragments (A-operand): lane holds Q[ri0+ln][kt*32 + g*8 + e]
    s16x8 qf[4];
#pragma unroll
    for (int kt = 0; kt < 4; ++kt)
        qf[kt] = *(const s16x8*)(Qbf + (size_t)(ri0 + ln) * DIM + kt * 32 + g * 8);

    f32x4 zero = {0.f, 0.f, 0.f, 0.f};
    f32x4 acc[8];
#pragma unroll
    for (int dt = 0; dt < 8; ++dt) acc[dt] = zero;
    float mrow[4], lrow[4];
#pragma unroll
    for (int r = 0; r < 4; ++r) { mrow[r] = -__builtin_inff(); lrow[r] = 0.f; }

    __hip_bfloat16* pme = Plds + w * (16 * 40);

    for (int jt0 = 0; jt0 < MCOLS; jt0 += BJ) {
        __syncthreads();
        // stage K tile [128][128] and Vt tile [128][128] into padded LDS
#pragma unroll
        for (int c = 0; c < 4; ++c) {
            int e = tid + 512 * c;
            int row = e >> 4, col8 = e & 15;
            int4 kv = *(const int4*)(Kbf + (size_t)(jt0 + row) * DIM + col8 * 8);
            *(int4*)(Klds + row * LSTRIDE + col8 * 8) = kv;
            int4 vv = *(const int4*)(Vt + (size_t)row * MCOLS + jt0 + col8 * 8);
            *(int4*)(Vlds + row * LSTRIDE + col8 * 8) = vv;
        }
        __syncthreads();

        // adjacency (issue early; independent of LDS)
        int am[2][4];
#pragma unroll
        for (int jt = 0; jt < 2; ++jt)
#pragma unroll
            for (int r = 0; r < 4; ++r)
                am[jt][r] = adj[(size_t)(ri0 + g * 4 + r) * MCOLS + jt0 + wj * 32 + jt * 16 + ln];

        // S = Q K^T  (wave's 16 rows x 32 cols)
        f32x4 s[2];
#pragma unroll
        for (int jt = 0; jt < 2; ++jt) {
            s[jt] = zero;
#pragma unroll
            for (int kt = 0; kt < 4; ++kt) {
                s16x8 kfrag = *(const s16x8*)(Klds + (wj * 32 + jt * 16 + ln) * LSTRIDE + kt * 32 + g * 8);
                s[jt] = __builtin_amdgcn_mfma_f32_16x16x32_bf16(qf[kt], kfrag, s[jt], 0, 0, 0);
            }
        }

        // mask + online softmax (rows live in 16-lane groups, reg r = row)
        float p0v[4], p1v[4];
#pragma unroll
        for (int r = 0; r < 4; ++r) {
            float s0 = am[0][r] ? s[0][r] : s[0][r] - NEGV;
            float s1 = am[1][r] ? s[1][r] : s[1][r] - NEGV;
            float vm = fmaxf(s0, s1);
            vm = fmaxf(vm, __shfl_xor(vm, 1));
            vm = fmaxf(vm, __shfl_xor(vm, 2));
            vm = fmaxf(vm, __shfl_xor(vm, 4));
            vm = fmaxf(vm, __shfl_xor(vm, 8));
            float mnew = fmaxf(mrow[r], vm);
            float scale = __expf(mrow[r] - mnew);
            mrow[r] = mnew;
            float p0 = __expf(s0 - mnew);
            float p1 = __expf(s1 - mnew);
            float vs = p0 + p1;
            vs += __shfl_xor(vs, 1);
            vs += __shfl_xor(vs, 2);
            vs += __shfl_xor(vs, 4);
            vs += __shfl_xor(vs, 8);
            lrow[r] = lrow[r] * scale + vs;
            p0v[r] = p0; p1v[r] = p1;
#pragma unroll
            for (int dt = 0; dt < 8; ++dt) acc[dt][r] *= scale;
        }

        // P -> LDS (bf16), per-wave private buffer [16][40]
#pragma unroll
        for (int r = 0; r < 4; ++r) {
            pme[(g * 4 + r) * 40 + ln]      = __float2bfloat16(p0v[r]);
            pme[(g * 4 + r) * 40 + 16 + ln] = __float2bfloat16(p1v[r]);
        }

        // PV: A = P (k=32), B = Vt fragments
        s16x8 pfrag = *(const s16x8*)(pme + ln * 40 + g * 8);
#pragma unroll
        for (int dt = 0; dt < 8; ++dt) {
            s16x8 vfrag = *(const s16x8*)(Vlds + (dt * 16 + ln) * LSTRIDE + wj * 32 + g * 8);
            acc[dt] = __builtin_amdgcn_mfma_f32_16x16x32_bf16(pfrag, vfrag, acc[dt], 0, 0, 0);
        }
    }

    // merge 4 j-slice partials per row via LDS
    __syncthreads();
    float* Opart  = (float*)smem;              // [4][2][16][128] = 64 KiB
    float* mlpart = (float*)(smem + 65536);    // [4][2][16][2]
#pragma unroll
    for (int dt = 0; dt < 8; ++dt)
#pragma unroll
        for (int r = 0; r < 4; ++r)
            Opart[((wj * 2 + wi) * 16 + g * 4 + r) * 128 + dt * 16 + ln] = acc[dt][r];
    if (ln == 0) {
#pragma unroll
        for (int r = 0; r < 4; ++r) {
            mlpart[((wj * 2 + wi) * 16 + g * 4 + r) * 2]     = mrow[r];
            mlpart[((wj * 2 + wi) * 16 + g * 4 + r) * 2 + 1] = lrow[r];
        }
    }
    __syncthreads();

    int il = tid >> 4;          // 0..31 output row within block
    int d0 = (tid & 15) * 8;    // 0..120
    int wi2 = il >> 4, r2 = il & 15;
    float M = -__builtin_inff();
#pragma unroll
    for (int p2 = 0; p2 < 4; ++p2)
        M = fmaxf(M, mlpart[((p2 * 2 + wi2) * 16 + r2) * 2]);
    float L = 0.f, o[8];
#pragma unroll
    for (int k = 0; k < 8; ++k) o[k] = 0.f;
#pragma unroll
    for (int p2 = 0; p2 < 4; ++p2) {
        float mw  = mlpart[((p2 * 2 + wi2) * 16 + r2) * 2];
        float lw  = mlpart[((p2 * 2 + wi2) * 16 + r2) * 2 + 1];
        float wgt = __expf(mw - M);
        L += lw * wgt;
        const float* op = Opart + ((p2 * 2 + wi2) * 16 + r2) * 128 + d0;
#pragma unroll
        for (int k = 0; k < 8; ++k) o[k] += op[k] * wgt;
    }
    float inv = 1.0f / L;
    float4 o0 = {o[0] * inv, o[1] * inv, o[2] * inv, o[3] * inv};
    float4 o1 = {o[4] * inv, o[5] * inv, o[6] * inv, o[7] * inv};
    float* outp = out + (size_t)(i0 + il) * DIM + d0;
    *(float4*)outp = o0;
    *(float4*)(outp + 4) = o1;
}

extern "C" void kernel_launch(void* const* d_in, const int* in_sizes, int n_in,
                              void* d_out, int out_size, void* d_ws, size_t ws_size,
                              hipStream_t stream) {
    const float* xi   = (const float*)d_in[0];
    const float* xj   = (const float*)d_in[1];
    const int*   adj  = (const int*)d_in[2];
    const float* beta = (const float*)d_in[3];
    float* out = (float*)d_out;

    char* ws = (char*)d_ws;
    __hip_bfloat16* Qbf = (__hip_bfloat16*)ws;                                   // 2 MiB
    __hip_bfloat16* Kbf = (__hip_bfloat16*)(ws + (size_t)NROWS * DIM * 2);       // 2 MiB
    __hip_bfloat16* Vt  = (__hip_bfloat16*)(ws + 2 * (size_t)NROWS * DIM * 2);   // 2 MiB

    hipLaunchKernelGGL(prep_scale_rows, dim3(2048), dim3(256), 0, stream, xi, beta, Qbf);
    hipLaunchKernelGGL(prep_scale_rows, dim3(2048), dim3(256), 0, stream, xj, (const float*)nullptr, Kbf);
    hipLaunchKernelGGL(prep_vt, dim3(128, 2), dim3(256), 0, stream, xj, Vt);
    hipLaunchKernelGGL(flash_attn, dim3(256), dim3(512), 0, stream, Qbf, Kbf, Vt, adj, out);
}

// Round 2
// 223.706 us; speedup vs baseline: 1.2865x; 1.2865x over previous
//
#include <hip/hip_runtime.h>
#include <hip/hip_bf16.h>

typedef float f32x4 __attribute__((ext_vector_type(4)));
typedef short s16x8 __attribute__((ext_vector_type(8)));

#define NROWS 8192
#define MCOLS 8192
#define DIM   128
#define NEGV  1e9f
#define BI    32
#define NTILE 256   // MCOLS / 32

// ---- prep: per-row norm + scale + bf16 convert (row-major out) ----
__global__ void prep_scale_rows(const float* __restrict__ x,
                                const float* __restrict__ beta,
                                __hip_bfloat16* __restrict__ outbf) {
    int row = blockIdx.x * 4 + (threadIdx.x >> 6);
    int l = threadIdx.x & 63;
    const float* xr = x + (size_t)row * DIM;
    float x0 = xr[l], x1 = xr[l + 64];
    float ss = x0 * x0 + x1 * x1;
#pragma unroll
    for (int off = 32; off >= 1; off >>= 1) ss += __shfl_xor(ss, off);
    float s = (beta ? beta[0] : 1.0f) / sqrtf(ss);
    __hip_bfloat16* o = outbf + (size_t)row * DIM;
    o[l]      = __float2bfloat16(x0 * s);
    o[l + 64] = __float2bfloat16(x1 * s);
}

// ---- prep: transpose xj -> Vt[d][j] bf16 (raw values) ----
__global__ void prep_vt(const float* __restrict__ xj, __hip_bfloat16* __restrict__ vt) {
    __shared__ float tile[64][65];
    int j0 = blockIdx.x * 64;
    int d0 = blockIdx.y * 64;
    int t = threadIdx.x; // 256
#pragma unroll
    for (int c = 0; c < 16; ++c) {
        int idx = t + 256 * c;
        int jr = idx >> 6, dc = idx & 63;
        tile[jr][dc] = xj[(size_t)(j0 + jr) * DIM + d0 + dc];
    }
    __syncthreads();
#pragma unroll
    for (int c = 0; c < 16; ++c) {
        int idx = t + 256 * c;
        int dr = idx >> 6, jc = idx & 63;
        vt[(size_t)(d0 + dr) * MCOLS + j0 + jc] = __float2bfloat16(tile[jc][dr]);
    }
}

// ---- pack adjacency int32 -> bitmask (1 bit per entry) via wave ballot ----
__global__ __launch_bounds__(256) void pack_adj(const int* __restrict__ adj,
                                                unsigned long long* __restrict__ bm) {
    const int lane = threadIdx.x & 63;
    const int gw = (int)((blockIdx.x * 256 + threadIdx.x) >> 6); // 0..8191
#pragma unroll 4
    for (int it = 0; it < 128; ++it) {
        size_t w = (size_t)gw + 8192u * (size_t)it;
        int a = adj[w * 64 + lane];
        unsigned long long b = __ballot(a != 0);
        if (lane == 0) bm[w] = b;
    }
}

// ---- flash attention, barrier-free main loop, fragments direct from L2 ----
template <bool PACKED>
__global__ __launch_bounds__(512, 2) void flash2(const __hip_bfloat16* __restrict__ Qbf,
                                                 const __hip_bfloat16* __restrict__ Kbf,
                                                 const __hip_bfloat16* __restrict__ Vt,
                                                 const unsigned int* __restrict__ bmp,
                                                 const int* __restrict__ adjp,
                                                 float* __restrict__ out) {
    __shared__ char smem[66560];
    __hip_bfloat16* Plds = (__hip_bfloat16*)smem;

    const int tid  = threadIdx.x;
    const int w    = tid >> 6;
    const int lane = tid & 63;
    const int g    = lane >> 4;
    const int ln   = lane & 15;
    const int i0   = blockIdx.x * BI;

    // Q fragments: A-operand, rows i0 + rg*16 + ln
    s16x8 qf[2][4];
#pragma unroll
    for (int rg = 0; rg < 2; ++rg)
#pragma unroll
        for (int kt = 0; kt < 4; ++kt)
            qf[rg][kt] = *(const s16x8*)(Qbf + (size_t)(i0 + rg * 16 + ln) * DIM + kt * 32 + g * 8);

    f32x4 zero = {0.f, 0.f, 0.f, 0.f};
    f32x4 acc[2][8];
#pragma unroll
    for (int rg = 0; rg < 2; ++rg)
#pragma unroll
        for (int dt = 0; dt < 8; ++dt) acc[rg][dt] = zero;
    float mr[2][4], lr[2][4];
#pragma unroll
    for (int rg = 0; rg < 2; ++rg)
#pragma unroll
        for (int r = 0; r < 4; ++r) { mr[rg][r] = -__builtin_inff(); lr[rg][r] = 0.f; }

    __hip_bfloat16* pbase = Plds + w * 1280; // [2rg][16 rows][40]

    // wave w handles tiles t = w, w+8, ... (32-col tiles)
    for (int t = w; t < NTILE; t += 8) {
        const int jt = t * 32;

        // mask words / raw mask (issued first, independent)
        unsigned int bw[2][4];
        int am[2][4][2];
        if constexpr (PACKED) {
#pragma unroll
            for (int rg = 0; rg < 2; ++rg)
#pragma unroll
                for (int r = 0; r < 4; ++r)
                    bw[rg][r] = bmp[(size_t)(i0 + rg * 16 + g * 4 + r) * NTILE + t];
        } else {
#pragma unroll
            for (int rg = 0; rg < 2; ++rg)
#pragma unroll
                for (int r = 0; r < 4; ++r)
#pragma unroll
                    for (int jt2 = 0; jt2 < 2; ++jt2)
                        am[rg][r][jt2] = adjp[(size_t)(i0 + rg * 16 + g * 4 + r) * MCOLS + jt + jt2 * 16 + ln];
        }

        // K fragments (shared across row groups): rows jt + jt2*16 + ln
        s16x8 kf[2][4];
#pragma unroll
        for (int jt2 = 0; jt2 < 2; ++jt2)
#pragma unroll
            for (int kt = 0; kt < 4; ++kt)
                kf[jt2][kt] = *(const s16x8*)(Kbf + (size_t)(jt + jt2 * 16 + ln) * DIM + kt * 32 + g * 8);

        // V fragments: Vt[dt*16+ln][jt + g*8 ..]
        s16x8 vf[8];
#pragma unroll
        for (int dt = 0; dt < 8; ++dt)
            vf[dt] = *(const s16x8*)(Vt + (size_t)(dt * 16 + ln) * MCOLS + jt + g * 8);

        // S = Q K^T
        f32x4 s[2][2];
#pragma unroll
        for (int rg = 0; rg < 2; ++rg)
#pragma unroll
            for (int jt2 = 0; jt2 < 2; ++jt2) {
                s[rg][jt2] = zero;
#pragma unroll
                for (int kt = 0; kt < 4; ++kt)
                    s[rg][jt2] = __builtin_amdgcn_mfma_f32_16x16x32_bf16(qf[rg][kt], kf[jt2][kt], s[rg][jt2], 0, 0, 0);
            }

        // mask + online softmax; rows = rg*16 + g*4 + r, cols = jt + jt2*16 + ln
#pragma unroll
        for (int rg = 0; rg < 2; ++rg)
#pragma unroll
            for (int r = 0; r < 4; ++r) {
                bool b0, b1;
                if constexpr (PACKED) {
                    b0 = (bw[rg][r] >> ln) & 1;
                    b1 = (bw[rg][r] >> (16 + ln)) & 1;
                } else {
                    b0 = am[rg][r][0] != 0;
                    b1 = am[rg][r][1] != 0;
                }
                float s0 = b0 ? s[rg][0][r] : s[rg][0][r] - NEGV;
                float s1 = b1 ? s[rg][1][r] : s[rg][1][r] - NEGV;
                float vm = fmaxf(s0, s1);
                vm = fmaxf(vm, __shfl_xor(vm, 1));
                vm = fmaxf(vm, __shfl_xor(vm, 2));
                vm = fmaxf(vm, __shfl_xor(vm, 4));
                vm = fmaxf(vm, __shfl_xor(vm, 8));
                float mnew = fmaxf(mr[rg][r], vm);
                float sc = __expf(mr[rg][r] - mnew);
                mr[rg][r] = mnew;
                float p0 = __expf(s0 - mnew);
                float p1 = __expf(s1 - mnew);
                float vs = p0 + p1;
                vs += __shfl_xor(vs, 1);
                vs += __shfl_xor(vs, 2);
                vs += __shfl_xor(vs, 4);
                vs += __shfl_xor(vs, 8);
                lr[rg][r] = lr[rg][r] * sc + vs;
#pragma unroll
                for (int dt = 0; dt < 8; ++dt) acc[rg][dt][r] *= sc;
                pbase[(rg * 16 + g * 4 + r) * 40 + ln]      = __float2bfloat16(p0);
                pbase[(rg * 16 + g * 4 + r) * 40 + 16 + ln] = __float2bfloat16(p1);
            }

        // PV (same-wave LDS RAW; compiler inserts lgkmcnt wait)
#pragma unroll
        for (int rg = 0; rg < 2; ++rg) {
            s16x8 pf = *(const s16x8*)(pbase + (rg * 16 + ln) * 40 + g * 8);
#pragma unroll
            for (int dt = 0; dt < 8; ++dt)
                acc[rg][dt] = __builtin_amdgcn_mfma_f32_16x16x32_bf16(pf, vf[dt], acc[rg][dt], 0, 0, 0);
        }
    }

    // ---- merge 8 j-slice partials, one row-group at a time ----
    float* Opart = (float*)smem;            // [8][16][128] = 64 KiB
    float* mlp   = (float*)(smem + 65536);  // [8][16][2]
#pragma unroll
    for (int rg = 0; rg < 2; ++rg) {
        __syncthreads();
#pragma unroll
        for (int dt = 0; dt < 8; ++dt)
#pragma unroll
            for (int r = 0; r < 4; ++r)
                Opart[(w * 16 + g * 4 + r) * 128 + dt * 16 + ln] = acc[rg][dt][r];
        if (ln == 0) {
#pragma unroll
            for (int r = 0; r < 4; ++r) {
                mlp[(w * 16 + g * 4 + r) * 2]     = mr[rg][r];
                mlp[(w * 16 + g * 4 + r) * 2 + 1] = lr[rg][r];
            }
        }
        __syncthreads();
        int r2 = tid >> 5;          // 0..15
        int d0 = (tid & 31) * 4;    // 0..124
        float M = -__builtin_inff();
#pragma unroll
        for (int p = 0; p < 8; ++p) M = fmaxf(M, mlp[(p * 16 + r2) * 2]);
        float L = 0.f, o[4] = {0.f, 0.f, 0.f, 0.f};
#pragma unroll
        for (int p = 0; p < 8; ++p) {
            float wgt = __expf(mlp[(p * 16 + r2) * 2] - M);
            L += mlp[(p * 16 + r2) * 2 + 1] * wgt;
            const float* op = Opart + (p * 16 + r2) * 128 + d0;
#pragma unroll
            for (int k = 0; k < 4; ++k) o[k] += op[k] * wgt;
        }
        float inv = 1.0f / L;
        float4 ov = {o[0] * inv, o[1] * inv, o[2] * inv, o[3] * inv};
        *(float4*)(out + (size_t)(i0 + rg * 16 + r2) * DIM + d0) = ov;
    }
}

extern "C" void kernel_launch(void* const* d_in, const int* in_sizes, int n_in,
                              void* d_out, int out_size, void* d_ws, size_t ws_size,
                              hipStream_t stream) {
    const float* xi   = (const float*)d_in[0];
    const float* xj   = (const float*)d_in[1];
    const int*   adj  = (const int*)d_in[2];
    const float* beta = (const float*)d_in[3];
    float* out = (float*)d_out;

    char* ws = (char*)d_ws;
    __hip_bfloat16* Qbf = (__hip_bfloat16*)ws;                                   // 2 MiB
    __hip_bfloat16* Kbf = (__hip_bfloat16*)(ws + (size_t)NROWS * DIM * 2);       // 2 MiB
    __hip_bfloat16* Vt  = (__hip_bfloat16*)(ws + 2 * (size_t)NROWS * DIM * 2);   // 2 MiB
    unsigned long long* bm = (unsigned long long*)(ws + 3 * (size_t)NROWS * DIM * 2); // 8 MiB
    size_t need = 3 * (size_t)NROWS * DIM * 2 + (size_t)NROWS * (MCOLS / 8);

    hipLaunchKernelGGL(prep_scale_rows, dim3(2048), dim3(256), 0, stream, xi, beta, Qbf);
    hipLaunchKernelGGL(prep_scale_rows, dim3(2048), dim3(256), 0, stream, xj, (const float*)nullptr, Kbf);
    hipLaunchKernelGGL(prep_vt, dim3(128, 2), dim3(256), 0, stream, xj, Vt);

    if (ws_size >= need) {
        hipLaunchKernelGGL(pack_adj, dim3(2048), dim3(256), 0, stream, adj, bm);
        hipLaunchKernelGGL((flash2<true>), dim3(NROWS / BI), dim3(512), 0, stream,
                           Qbf, Kbf, Vt, (const unsigned int*)bm, (const int*)nullptr, out);
    } else {
        hipLaunchKernelGGL((flash2<false>), dim3(NROWS / BI), dim3(512), 0, stream,
                           Qbf, Kbf, Vt, (const unsigned int*)nullptr, adj, out);
    }
}